// Round 1
// baseline (4576.256 us; speedup 1.0000x reference)
//
#include <hip/hip_runtime.h>
#include <hip/hip_bf16.h>
#include <math.h>

// Problem constants (match reference)
#define BB 4
#define PP 32768
#define TOPK 5000
#define NB 4096          // score buckets for ranking
#define NW 157           // ceil(5000/32) bit-words for alive mask

// ws layout (bytes), all 16B-aligned
#define BOXES_OFF   0u          // float4[BB*PP]        = 2097152
#define HIST_OFF    2097152u    // uint[BB*NB]          = 65536
#define START_OFF   2162688u    // uint[BB*NB]          = 65536
#define CNT_OFF     2228224u    // uint[BB*NB]          = 65536
#define NV_OFF      2293760u    // int[BB] nvalid
#define NC_OFF      2293792u    // int[BB] ncand
#define GIDX_OFF    2294016u    // uint[BB*PP]          = 524288
#define GSC_OFF     2818304u    // float[BB*PP]         = 524288
#define CS_OFF      3342592u    // float[BB*TOPK]       = 80000 (pad to 80128)
#define CB_OFF      3422720u    // float4[BB*TOPK]      = 320000
#define WS_NEEDED   3742720u

__global__ __launch_bounds__(256) void decode_hist_kernel(
    const float4* __restrict__ loc, const float2* __restrict__ conf,
    const float4* __restrict__ prior, float4* __restrict__ boxes,
    unsigned* __restrict__ hist)
{
#pragma clang fp contract(off)
    int i = blockIdx.x * 256 + threadIdx.x;
    if (i >= BB * PP) return;
    int b = i >> 15;
    int p = i & (PP - 1);
    float4 l = loc[i];
    float4 pr = prior[p];
    float s = conf[i].y;
    // cxcy = prior[:2] + (loc[:2] * 0.1) * prior[2:]
    float cx = pr.x + (l.x * 0.1f) * pr.z;
    float cy = pr.y + (l.y * 0.1f) * pr.w;
    // wh = prior[2:] * exp(loc[2:] * 0.2)
    float w = pr.z * expf(l.z * 0.2f);
    float h = pr.w * expf(l.w * 0.2f);
    float4 bx;
    bx.x = cx - 0.5f * w;
    bx.y = cy - 0.5f * h;
    bx.z = cx + 0.5f * w;
    bx.w = cy + 0.5f * h;
    boxes[i] = bx;
    if (s > 0.05f) {
        int bk = (int)(s * 4096.0f);
        bk = bk < 0 ? 0 : (bk > NB - 1 ? NB - 1 : bk);
        atomicAdd(&hist[b * NB + bk], 1u);
    }
}

__global__ __launch_bounds__(256) void scan_hist_kernel(
    const unsigned* __restrict__ hist, unsigned* __restrict__ start,
    int* __restrict__ nvalid, int* __restrict__ ncand)
{
    int b = blockIdx.x;
    int t = threadIdx.x;
    __shared__ unsigned sums[256];
    unsigned local[16];
    unsigned s = 0;
    const unsigned* hb = hist + b * NB;
    #pragma unroll
    for (int k = 0; k < 16; k++) {
        unsigned v = hb[t * 16 + k];
        local[k] = s;
        s += v;
    }
    sums[t] = s;
    __syncthreads();
    // Hillis-Steele inclusive scan over 256 partial sums
    for (int off = 1; off < 256; off <<= 1) {
        unsigned v = (t >= off) ? sums[t - off] : 0u;
        __syncthreads();
        sums[t] += v;
        __syncthreads();
    }
    unsigned excl = sums[t] - s;
    unsigned* sb = start + b * NB;
    #pragma unroll
    for (int k = 0; k < 16; k++) sb[t * 16 + k] = excl + local[k];
    if (t == 255) {
        nvalid[b] = (int)sums[255];
        ncand[b] = sums[255] < (unsigned)TOPK ? (int)sums[255] : TOPK;
    }
}

__global__ __launch_bounds__(256) void scatter_group_kernel(
    const float2* __restrict__ conf, const unsigned* __restrict__ start,
    unsigned* __restrict__ cnt, unsigned* __restrict__ gidx,
    float* __restrict__ gscore)
{
    int i = blockIdx.x * 256 + threadIdx.x;
    if (i >= BB * PP) return;
    int b = i >> 15;
    int p = i & (PP - 1);
    float s = conf[i].y;
    if (s > 0.05f) {
        int bk = (int)(s * 4096.0f);
        bk = bk < 0 ? 0 : (bk > NB - 1 ? NB - 1 : bk);
        unsigned o = atomicAdd(&cnt[b * NB + bk], 1u);
        unsigned pos = start[b * NB + bk] + o;
        gidx[b * PP + pos] = (unsigned)p;
        gscore[b * PP + pos] = s;
    }
}

__global__ __launch_bounds__(256) void rank_topk_kernel(
    const unsigned* __restrict__ gidx, const float* __restrict__ gscore,
    const unsigned* __restrict__ start, const unsigned* __restrict__ hist,
    const int* __restrict__ nvalid, const float4* __restrict__ boxes,
    float* __restrict__ cs, float4* __restrict__ cb)
{
#pragma clang fp contract(off)
    int i = blockIdx.x * 256 + threadIdx.x;
    if (i >= BB * PP) return;
    int b = i >> 15;
    int pos = i & (PP - 1);
    int nv = nvalid[b];
    if (pos >= nv) return;
    float s = gscore[b * PP + pos];
    unsigned p = gidx[b * PP + pos];
    int bk = (int)(s * 4096.0f);
    bk = bk < 0 ? 0 : (bk > NB - 1 ? NB - 1 : bk);
    unsigned st = start[b * NB + bk];
    unsigned c = hist[b * NB + bk];
    // elements strictly above this bucket
    unsigned rank = (unsigned)nv - st - c;
    const float* gs = gscore + b * PP + st;
    const unsigned* gi = gidx + b * PP + st;
    for (unsigned k = 0; k < c; k++) {
        float sk = gs[k];
        unsigned pk = gi[k];
        // stable descending: higher score first; tie -> smaller index first
        if (sk > s || (sk == s && pk < p)) rank++;
    }
    if (rank < (unsigned)TOPK) {
        cs[b * TOPK + rank] = s;
        cb[(size_t)b * TOPK + rank] = boxes[b * PP + p];
    }
}

__global__ __launch_bounds__(256) void nms_kernel(
    const float* __restrict__ cs, const float4* __restrict__ cb,
    const int* __restrict__ ncand, float* __restrict__ out)
{
#pragma clang fp contract(off)
    int b = blockIdx.x;
    int t = threadIdx.x;
    __shared__ unsigned alive[NW];
    __shared__ int jslot;
    __shared__ int kslot;
    int nc = ncand[b];
    // init alive mask: bits [0, nc)
    for (int w = t; w < NW; w += 256) {
        int lo = w * 32;
        unsigned m = 0u;
        if (lo + 32 <= nc) m = 0xffffffffu;
        else if (lo < nc) m = (1u << (nc - lo)) - 1u;
        alive[w] = m;
    }
    if (t == 0) kslot = 0;
    __syncthreads();

    const float* csb = cs + b * TOPK;
    const float4* cbb = cb + (size_t)b * TOPK;
    float* outb = out + ((size_t)b * 2 + 1) * TOPK * 5;

    for (int iter = 0; iter <= TOPK; iter++) {
        // --- find lowest-index alive candidate (wave 0 only) ---
        if (t < 64) {
            unsigned a0 = alive[t];
            unsigned a1 = (t + 64 < NW) ? alive[t + 64] : 0u;
            unsigned a2 = (t + 128 < NW) ? alive[t + 128] : 0u;
            unsigned long long b0 = __ballot(a0 != 0u);
            unsigned long long b1 = __ballot(a1 != 0u);
            unsigned long long b2 = __ballot(a2 != 0u);
            int j = -1;
            int w = -1;
            if (b0) w = (int)__builtin_ctzll(b0);
            else if (b1) w = 64 + (int)__builtin_ctzll(b1);
            else if (b2) w = 128 + (int)__builtin_ctzll(b2);
            if (w >= 0) {
                unsigned aw = alive[w];
                j = w * 32 + (int)__builtin_ctz(aw);
            }
            if (t == 0) jslot = j;
        }
        __syncthreads();
        int j = jslot;
        if (j < 0) break;

        float4 bj = cbb[j];   // broadcast load
        if (t == 0) {
            float sj = csb[j];
            int k = kslot++;
            float* row = outb + (size_t)k * 5;
            row[0] = sj;
            row[1] = bj.x;
            row[2] = bj.y;
            row[3] = bj.z;
            row[4] = bj.w;
            alive[j >> 5] &= ~(1u << (j & 31));  // self-clear (IoU(j,j) may be NaN)
        }
        __syncthreads();

        // --- suppression pass: clear alive bits with IoU > 0.3 ---
        float ax1 = bj.x, ay1 = bj.y, ax2 = bj.z, ay2 = bj.w;
        float areaj = (ax2 - ax1) * (ay2 - ay1);
        for (int c = t; c < TOPK; c += 256) {
            float4 bc = cbb[c];
            float iw = fminf(ax2, bc.z) - fmaxf(ax1, bc.x);
            iw = fmaxf(iw, 0.0f);
            float ih = fminf(ay2, bc.w) - fmaxf(ay1, bc.y);
            ih = fmaxf(ih, 0.0f);
            float inter = iw * ih;
            float areac = (bc.z - bc.x) * (bc.w - bc.y);
            float uni = areaj + areac - inter;
            bool sup = (inter / uni) > 0.3f;   // NaN -> false, matches jnp
            unsigned long long m = __ballot(sup);
            int lane = t & 63;
            int base = c - lane;               // 64-aligned
            if (lane == 0)  alive[(base >> 5)]     &= ~(unsigned)(m & 0xffffffffull);
            if (lane == 32) alive[(base >> 5) + 1] &= ~(unsigned)(m >> 32);
        }
        __syncthreads();
    }
}

extern "C" void kernel_launch(void* const* d_in, const int* in_sizes, int n_in,
                              void* d_out, int out_size, void* d_ws, size_t ws_size,
                              hipStream_t stream) {
    if (ws_size < WS_NEEDED) return;  // fail loudly (wrong output) rather than corrupt

    const float4* loc = (const float4*)d_in[0];
    const float2* conf = (const float2*)d_in[1];
    const float4* prior = (const float4*)d_in[2];
    float* out = (float*)d_out;

    char* ws = (char*)d_ws;
    float4* boxes = (float4*)(ws + BOXES_OFF);
    unsigned* hist = (unsigned*)(ws + HIST_OFF);
    unsigned* start = (unsigned*)(ws + START_OFF);
    unsigned* cnt = (unsigned*)(ws + CNT_OFF);
    int* nvalid = (int*)(ws + NV_OFF);
    int* ncand = (int*)(ws + NC_OFF);
    unsigned* gidx = (unsigned*)(ws + GIDX_OFF);
    float* gscore = (float*)(ws + GSC_OFF);
    float* cs = (float*)(ws + CS_OFF);
    float4* cb = (float4*)(ws + CB_OFF);

    // zero output + counters
    hipMemsetAsync(d_out, 0, (size_t)out_size * sizeof(float), stream);
    hipMemsetAsync(hist, 0, (size_t)BB * NB * sizeof(unsigned), stream);
    hipMemsetAsync(cnt, 0, (size_t)BB * NB * sizeof(unsigned), stream);

    int nblk = (BB * PP + 255) / 256;
    decode_hist_kernel<<<nblk, 256, 0, stream>>>(loc, conf, prior, boxes, hist);
    scan_hist_kernel<<<BB, 256, 0, stream>>>(hist, start, nvalid, ncand);
    scatter_group_kernel<<<nblk, 256, 0, stream>>>(conf, start, cnt, gidx, gscore);
    rank_topk_kernel<<<nblk, 256, 0, stream>>>(gidx, gscore, start, hist, nvalid,
                                               boxes, cs, cb);
    nms_kernel<<<BB, 256, 0, stream>>>(cs, cb, ncand, out);
}